// Round 7
// baseline (113.933 us; speedup 1.0000x reference)
//
#include <hip/hip_runtime.h>
#include <hip/hip_fp16.h>

// MacTensorUnit — R7. Structure (R4): x3 = F(x0) with F = f∘f∘f a UNIVERSAL
// scalar map -> kernel 1 tabulates F (4096 node-pair half2 entries, [-8,8]);
// kernel 2: expansion -> LDS-LUT lerp -> gate -> sum4. |x|>8: sigmoids
// saturate exactly in fp32 -> affine tails, slopes cP^3/cN^3 from runtime
// arrays (slopeP ~1.48 for these inputs — tail correction is REQUIRED).
//
// R7 (theory: load-latency bound; R6's depth-1 prefetch (~350 issue-cyc) is
// shorter than the ~500-cyc L3 data latency): rolling depth-2 register
// prefetch (~700 issue-cyc of slack) at only +12 VGPRs, preserving ~6
// waves/SIMD. cc-pairing + nontemporal stores kept from R6.

#define STEP2f    0.11110889f          // 0.33333^2
#define INV_2PI   0.15915494309189535f
#define LOG2E     1.4426950408889634f
#define LUT_N     4096
#define LUT_B     8.0f
#define LUT_SCALE 256.0f               // LUT_N / (2*LUT_B)
#define BPT       8                    // batches per thread (grid.y = 256/BPT)

struct MacCoef {
    float ca1, ca3, cb1, cb3;   // logistic-Phi poly, -log2e folded
    float A0r, dAr;             // angle affine, revolutions
    float V0s, dVs;             // velocity affine * STEP^2
};

__device__ __forceinline__ MacCoef make_coef(const float* angles, const float* velocity) {
    MacCoef c;
    c.ca1 = -1.5957691216f * LOG2E;
    c.ca3 = -0.0713548168f * LOG2E;
    c.cb1 = c.ca1 * 1.41421356237f;
    c.cb3 = c.ca3 * 2.82842712475f;
    c.A0r = angles[0] * INV_2PI;
    c.dAr = (angles[4] - angles[0]) * 1.25f * INV_2PI;
    c.V0s = velocity[0] * STEP2f;
    c.dVs = (velocity[4] - velocity[0]) * 1.25f * STEP2f;
    return c;
}

// one exact MAC step (R3 math: 2 exp2 + shared rcp + hw sin/cos)
__device__ __forceinline__ float mac_step(float x, const MacCoef& c) {
    float xx = x * x;
    float ua = fminf(x * fmaf(c.ca3, xx, c.ca1), 60.0f);
    float ub = fminf(x * fmaf(c.cb3, xx, c.cb1), 60.0f);
    float ea = __builtin_amdgcn_exp2f(ua);
    float eb = __builtin_amdgcn_exp2f(ub);
    float da = 1.0f + ea, db = 1.0f + eb;
    float rp = __builtin_amdgcn_rcpf(da * db);
    float sa = db * rp;                       // ngd(x)
    float sb = da * rp;                       // nerf(x)
    float r  = fmaf(c.dAr, sa, c.A0r);        // revolutions
    float v2 = fmaf(c.dVs, sb, c.V0s);
    float sn = __builtin_amdgcn_sinf(r);
    float cs = __builtin_amdgcn_cosf(r);
    return fmaf(v2, fmaf(x, sn, cs), x);
}

__device__ __forceinline__ float F3(float x, const MacCoef& c) {
    x = mac_step(x, c);
    x = mac_step(x, c);
    return mac_step(x, c);
}

// ------------- kernel 1: build node-pair half2 table into d_ws -------------
__global__ __launch_bounds__(256) void build_lut(
    const float* __restrict__ angles, const float* __restrict__ velocity,
    __half2* __restrict__ lut2)
{
    int i = blockIdx.x * 256 + threadIdx.x;      // 0 .. 4095
    if (i >= LUT_N) return;
    MacCoef c = make_coef(angles, velocity);
    float x0 = fmaf((float)i,       1.0f / LUT_SCALE, -LUT_B);
    float x1 = fmaf((float)(i + 1), 1.0f / LUT_SCALE, -LUT_B);
    lut2[i] = __halves2half2(__float2half(F3(x0, c)), __float2half(F3(x1, c)));
}

// ------------- kernel 2: expansion -> LUT lerp -> gate -> sum4 -------------
__global__ __launch_bounds__(256) void mac_kernel(
    const float* __restrict__ data,
    const float* __restrict__ in_w,
    const float* __restrict__ in_b,
    const float* __restrict__ out_w,
    const float* __restrict__ out_b,
    const float* __restrict__ angles,
    const float* __restrict__ velocity,
    const __half2* __restrict__ glut,
    float* __restrict__ out)
{
    __shared__ __half2 lut[LUT_N];               // 16 KB

    const int tid = threadIdx.x;
    // vectorized LDS fill: 4096 half2 = 1024 uint4
    {
        const uint4* src = (const uint4*)glut;
        uint4* dst = (uint4*)lut;
#pragma unroll
        for (int i = 0; i < 4; ++i) dst[tid + 256 * i] = src[tid + 256 * i];
    }

    const int t  = blockIdx.x * 256 + tid;       // 0 .. 12543 (= 256*49)
    const int os = t % 49;
    const int c  = t / 49;                       // data channel, 0..255

    const float* dptr = data + ((size_t)(blockIdx.y * BPT) * 256 + c) * 196 + os;
    float*       optr = out  + (size_t)(blockIdx.y * BPT) * 25088 + c * 98 + os;

    // rolling depth-2 register prefetch pipeline over batches
    float buf[3][4];
#pragma unroll
    for (int sf = 0; sf < 4; ++sf) buf[0][sf] = dptr[sf * 49];
#pragma unroll
    for (int sf = 0; sf < 4; ++sf) buf[1][sf] = dptr[50176 + sf * 49];

    MacCoef mc = make_coef(angles, velocity);
    // tail slopes: |x|>8 -> sigmoids saturated -> F affine, slope cP^3/cN^3
    float snp = __builtin_amdgcn_sinf(mc.A0r + mc.dAr);
    float cP  = fmaf(mc.V0s + mc.dVs, snp, 1.0f);
    float slopeP = cP * cP * cP;
    float snn = __builtin_amdgcn_sinf(mc.A0r);
    float cN  = fmaf(mc.V0s, snn, 1.0f);
    float slopeN = cN * cN * cN;

    // per-position weights for BOTH cc = 2c (e=0) and 2c+1 (e=1)
    float iw[2][4], ib[2][4], ow[2][4], ob[2][4];
    const int wb = c * 392 + os;                 // (2c)*196 + os
#pragma unroll
    for (int e = 0; e < 2; ++e)
#pragma unroll
        for (int sf = 0; sf < 4; ++sf) {
            int s = wb + e * 196 + sf * 49;
            iw[e][sf] = in_w[s];  ib[e][sf] = in_b[s];
            ow[e][sf] = out_w[s]; ob[e][sf] = out_b[s];
        }

    __syncthreads();

#pragma unroll
    for (int k = 0; k < BPT; ++k) {
        // prefetch batch k+2 (depth-2: ~700 issue-cycles of slack)
        if (k + 2 < BPT) {
            const float* dn = dptr + (size_t)(k + 2) * 50176;   // 256*196
#pragma unroll
            for (int sf = 0; sf < 4; ++sf) buf[(k + 2) % 3][sf] = dn[sf * 49];
        }

        float yv[2][4], tg[2][4];
#pragma unroll
        for (int sf = 0; sf < 4; ++sf) {
            float xv = buf[k % 3][sf];
#pragma unroll
            for (int e = 0; e < 2; ++e) {
                float x0 = fmaf(xv, iw[e][sf], ib[e][sf]);
                float xc = fminf(fmaxf(x0, -LUT_B), LUT_B);
                float fi = fmaf(xc, LUT_SCALE, 2048.0f);   // [0, 4096]
                int   j  = min((int)fi, LUT_N - 1);
                float fr = fi - (float)j;
                __half2 p = lut[j];                        // (F[j], F[j+1])
                float lo = __low2float(p), hi = __high2float(p);
                float v  = fmaf(fr, hi - lo, lo);          // interior F(x0)
                float dd = x0 - xc;                        // tails only
                float sl = x0 > 0.0f ? slopeP : slopeN;
                float y  = fmaf(dd, sl, v);
                yv[e][sf] = y;
                tg[e][sf] = fmaf(y, ow[e][sf], ob[e][sf]);
            }
        }

        // gate att = 0.5*tg/(1+|tg|)+0.5, shared rcp per pair (exact)
#pragma unroll
        for (int e = 0; e < 2; ++e) {
            float acc = 0.0f;
#pragma unroll
            for (int p = 0; p < 2; ++p) {
                float t0 = tg[e][2 * p], t1 = tg[e][2 * p + 1];
                float d0 = 1.0f + fabsf(t0);
                float d1 = 1.0f + fabsf(t1);
                float rr = __builtin_amdgcn_rcpf(d0 * d1);
                acc = fmaf(yv[e][2 * p],     fmaf(0.5f * t0, d1 * rr, 0.5f), acc);
                acc = fmaf(yv[e][2 * p + 1], fmaf(0.5f * t1, d0 * rr, 0.5f), acc);
            }
            __builtin_nontemporal_store(acc, optr + (size_t)k * 25088 + e * 49);
        }
    }
}

extern "C" void kernel_launch(void* const* d_in, const int* in_sizes, int n_in,
                              void* d_out, int out_size, void* d_ws, size_t ws_size,
                              hipStream_t stream) {
    const float* data   = (const float*)d_in[0];
    const float* in_w   = (const float*)d_in[1];
    const float* in_b   = (const float*)d_in[2];
    const float* out_w  = (const float*)d_in[3];
    const float* out_b  = (const float*)d_in[4];
    const float* angles = (const float*)d_in[5];
    const float* vel    = (const float*)d_in[6];
    float* out = (float*)d_out;
    __half2* lut = (__half2*)d_ws;               // 16 KB of scratch

    build_lut<<<dim3(LUT_N / 256), 256, 0, stream>>>(angles, vel, lut);

    dim3 grid(49, 256 / BPT);                    // 49*256 threads = 256*49 (c,os)
    mac_kernel<<<grid, 256, 0, stream>>>(data, in_w, in_b, out_w, out_b,
                                         angles, vel, lut, out);
}